// Round 13
// baseline (1102.144 us; speedup 1.0000x reference)
//
#include <hip/hip_runtime.h>
#include <hip/hip_bf16.h>
#include <cstdint>

// ---------------------------------------------------------------------------
// Attention block, bf16 MFMA pipeline:
//   cast -> fused QKV GEMM -> RoPE -> V transpose -> flash attention -> O GEMM
// Shapes: B=2 T=2048 DIM=4096 H=32 KVH=8 D=128, no mask, start_pos=0.
// KV mapping: jnp.tile -> Q-head h attends KV-head (h % 8).
// R6 (measured 821.3us, passed): va-hoist + cvt_pk + vectorized rope.
// R8 (5th resubmit after broker timeouts):
//   (1) attn Ps transit buffer [128][72](18KB) -> [64][64](8KB), slot-XOR
//       swizzled, reused per mi (write->read->write->read, same-wave DS
//       in-order). Total LDS 51200 -> 40960 = exactly 4 blocks/CU (was 3):
//       occupancy 12 -> 16 waves/CU. launch_bounds(256,4) caps VGPR at 128
//       (currently 108). Math bit-identical.
//   (2) gemm_bt: XCD-chunked blockIdx swizzle (T1; both grids %8==0 so the
//       simple bijective form is safe) for A-panel L2 locality.
// ---------------------------------------------------------------------------

typedef short bf16x8 __attribute__((ext_vector_type(8)));   // 8 bf16 = 4 VGPRs
typedef float f32x4  __attribute__((ext_vector_type(4)));

__device__ __forceinline__ float b2f(unsigned short h) {
  union { uint32_t u; float f; } v; v.u = ((uint32_t)h) << 16; return v.f;
}
__device__ __forceinline__ unsigned short f2b(float f) {
  union { float f; uint32_t u; } v; v.f = f;
  uint32_t r = (v.u + 0x7FFFu + ((v.u >> 16) & 1u)) >> 16;
  return (unsigned short)r;
}
// packed f32x2 -> bf16x2 (RTNE) in one instruction (T12 recipe)
__device__ __forceinline__ uint32_t cvt_pk_bf16(float lo, float hi) {
  uint32_t r;
  asm("v_cvt_pk_bf16_f32 %0, %1, %2" : "=v"(r) : "v"(lo), "v"(hi));
  return r;
}
__device__ __forceinline__ float lo2f(uint32_t u) {
  union { uint32_t u; float f; } w; w.u = u << 16; return w.f;
}
__device__ __forceinline__ float hi2f(uint32_t u) {
  union { uint32_t u; float f; } w; w.u = u & 0xffff0000u; return w.f;
}

#define GLDS16(gp, lp)                                                        \
  __builtin_amdgcn_global_load_lds(                                           \
      (const __attribute__((address_space(1))) unsigned int*)(gp),            \
      (__attribute__((address_space(3))) unsigned int*)(lp), 16, 0, 0)

// ---------------------------------------------------------------------------
// fp32 -> bf16 cast, 4 elements/thread
// ---------------------------------------------------------------------------
__global__ __launch_bounds__(256) void cast_f32_bf16(
    const float* __restrict__ in, unsigned short* __restrict__ out, int n4) {
  int i = blockIdx.x * 256 + threadIdx.x;
  if (i < n4) {
    float4 v = ((const float4*)in)[i];
    ushort4 o;
    o.x = f2b(v.x); o.y = f2b(v.y); o.z = f2b(v.z); o.w = f2b(v.w);
    ((ushort4*)out)[i] = o;
  }
}

// ---------------------------------------------------------------------------
// GEMM  C[m,n] = sum_k A[m,k]*B[n,k]
// R8: XCD-chunked swizzle — grid sizes 1536/1024 are both divisible by 8, so
// the simple (wg&7)*cpx + wg>>3 remap is bijective (guide T1/m157).
// ---------------------------------------------------------------------------
__device__ __forceinline__ void stout(float* p, float v) { *p = v; }
__device__ __forceinline__ void stout(unsigned short* p, float v) { *p = f2b(v); }

template <typename OUT>
__global__ __launch_bounds__(256, 2) void gemm_bt(
    const unsigned short* __restrict__ A, const unsigned short* __restrict__ B,
    OUT* __restrict__ C, int M, int N, int K) {
  __shared__ __align__(16) unsigned short As[128][64];  // 16 KB
  __shared__ __align__(16) unsigned short Bs[128][64];  // 16 KB

  const int tid  = threadIdx.x;
  const int lane = tid & 63;
  const int wave = tid >> 6;
  const int col  = lane & 15;
  const int quad = lane >> 4;

  // XCD-aware chunked swizzle (bijective: nwg % 8 == 0 for both launches)
  const int nwg = gridDim.x * gridDim.y;
  const int wg  = blockIdx.y * gridDim.x + blockIdx.x;
  const int cpx = nwg >> 3;
  const int swz = (wg & 7) * cpx + (wg >> 3);
  const int by  = swz / gridDim.x;
  const int bx  = swz - by * gridDim.x;
  const int bm = by * 128;
  const int bn = bx * 128;
  const int wm = (wave & 1) * 64;
  const int wn = (wave >> 1) * 64;

  f32x4 acc[4][4];
#pragma unroll
  for (int i = 0; i < 4; ++i)
#pragma unroll
    for (int j = 0; j < 4; ++j) acc[i][j] = (f32x4){0.f, 0.f, 0.f, 0.f};

  const int srow0  = tid >> 3;                    // 0..31
  const int gchunk = (tid & 7) ^ ((tid >> 3) & 7);
  const unsigned short* Ag = A + (size_t)(bm + srow0) * K + gchunk * 8;
  const unsigned short* Bg = B + (size_t)(bn + srow0) * K + gchunk * 8;
  unsigned short* Al = &As[0][0] + tid * 8;
  unsigned short* Bl = &Bs[0][0] + tid * 8;

  for (int k0 = 0; k0 < K; k0 += 64) {
    __syncthreads();
#pragma unroll
    for (int r = 0; r < 4; ++r) {
      GLDS16(Ag + k0 + (size_t)r * 32 * K, Al + r * 2048);
      GLDS16(Bg + k0 + (size_t)r * 32 * K, Bl + r * 2048);
    }
    __syncthreads();
#pragma unroll
    for (int ks = 0; ks < 2; ++ks) {
      bf16x8 a[4], b[4];
      const int slot = ((ks * 4 + quad) ^ (col & 7)) * 8;
#pragma unroll
      for (int i = 0; i < 4; ++i)
        a[i] = *(const bf16x8*)&As[wm + i * 16 + col][slot];
#pragma unroll
      for (int j = 0; j < 4; ++j)
        b[j] = *(const bf16x8*)&Bs[wn + j * 16 + col][slot];
#pragma unroll
      for (int i = 0; i < 4; ++i)
#pragma unroll
        for (int j = 0; j < 4; ++j)
          acc[i][j] = __builtin_amdgcn_mfma_f32_16x16x32_bf16(a[i], b[j],
                                                              acc[i][j], 0, 0, 0);
    }
  }

#pragma unroll
  for (int i = 0; i < 4; ++i) {
    int row = bm + wm + i * 16 + quad * 4;
#pragma unroll
    for (int j = 0; j < 4; ++j) {
      int cc = bn + wn + j * 16 + col;
#pragma unroll
      for (int r2 = 0; r2 < 4; ++r2)
        stout(C + (size_t)(row + r2) * N + cc, acc[i][j][r2]);
    }
  }
}

// ---------------------------------------------------------------------------
// RoPE in-place on qkv (4096 rows x 6144 cols): heads 0..31 = q, 32..39 = k.
// 4 rotations (16B) per thread; cvt_pk packing.
// grid: 4096*640/256 = 10240 blocks.
// ---------------------------------------------------------------------------
__global__ __launch_bounds__(256) void rope_qk(
    unsigned short* __restrict__ qkv, const float* __restrict__ cosT,
    const float* __restrict__ sinT) {
  int idx = blockIdx.x * 256 + threadIdx.x;  // < 4096*640
  int m = idx / 640;
  int p = idx - m * 640;                     // group of 4 pairs
  int head = p >> 4, i4 = p & 15;            // 16 groups of 4 pairs per head
  int t = m & 2047;
  unsigned short* ptr = qkv + (size_t)m * 6144 + head * 128 + i4 * 8;
  uint4 v = *(const uint4*)ptr;              // 4 (x,y) bf16 pairs
  float4 c = *(const float4*)&cosT[t * 64 + i4 * 4];
  float4 s = *(const float4*)&sinT[t * 64 + i4 * 4];
  float x0 = lo2f(v.x), y0 = hi2f(v.x);
  float x1 = lo2f(v.y), y1 = hi2f(v.y);
  float x2 = lo2f(v.z), y2 = hi2f(v.z);
  float x3 = lo2f(v.w), y3 = hi2f(v.w);
  uint4 o;
  o.x = cvt_pk_bf16(x0 * c.x - y0 * s.x, x0 * s.x + y0 * c.x);
  o.y = cvt_pk_bf16(x1 * c.y - y1 * s.y, x1 * s.y + y1 * c.y);
  o.z = cvt_pk_bf16(x2 * c.z - y2 * s.z, x2 * s.z + y2 * c.z);
  o.w = cvt_pk_bf16(x3 * c.w - y3 * s.w, x3 * s.w + y3 * c.w);
  *(uint4*)ptr = o;
}

// ---------------------------------------------------------------------------
// V transpose: vt[(b*8+kvh)*128 + d][s] = qkv[b*2048+s][5120 + kvh*128 + d]
// ---------------------------------------------------------------------------
__global__ __launch_bounds__(256) void transpose_v(
    const unsigned short* __restrict__ qkv, unsigned short* __restrict__ vt) {
  __shared__ unsigned short tile[64][72];
  int b = blockIdx.z >> 3, kvh = blockIdx.z & 7;
  int s0 = blockIdx.x * 64, d0 = blockIdx.y * 64;
  int tc = threadIdx.x & 63, tr = threadIdx.x >> 6;  // tr 0..3
#pragma unroll
  for (int r = 0; r < 16; ++r) {
    int row = r * 4 + tr;  // s within tile
    tile[row][tc] =
        qkv[(size_t)(b * 2048 + s0 + row) * 6144 + 5120 + kvh * 128 + d0 + tc];
  }
  __syncthreads();
#pragma unroll
  for (int r = 0; r < 16; ++r) {
    int drow = r * 4 + tr;  // d within tile
    vt[(size_t)((b * 8 + kvh) * 128 + d0 + drow) * 2048 + s0 + tc] =
        tile[tc][drow];
  }
}

// ---------------------------------------------------------------------------
// Flash attention, transposed-score formulation.
// grid (qt=16, h=32, b=2), 256 threads (4 waves), S-tile 64.
// S^T = K·Q^T  : lane owns Q-row q = wave*32+mi*16+(lane&15); 16 scores
//                in-lane per tile -> in-lane max/sum + shfl_xor(16,32).
// P transit: per-mi-reused Ps[64][64] (8KB), slot-XOR swizzle:
//   row rq = wave*16+col (wave-private), 8B slot = (j*4+quad) ^ (col&14).
//   Write 4x ds_write_b64 -> read 2x ds_read_b128 (slots (ks*8+quad*2)^c14,
//   +1 adjacent since c14 even) -> next mi reuses rows (same-wave DS
//   in-order).
// O^T = V^T·P  : A-frag from Vs (V^T tile, hoisted over mi), B-frag = bp regs.
// LDS: Ks 16KB + Vs 16KB + Ps 8KB = 40960 B -> exactly 4 blocks/CU.
// ---------------------------------------------------------------------------
__global__ __launch_bounds__(256, 4) void attn(
    const unsigned short* __restrict__ qkv, const unsigned short* __restrict__ vt,
    unsigned short* __restrict__ ctx) {
  constexpr int T = 2048, LD = 6144;
  const int qt = blockIdx.x, h = blockIdx.y, b = blockIdx.z;
  const int kvh = h & 7;  // jnp.tile semantics
  const int tid = threadIdx.x, lane = tid & 63, wave = tid >> 6;
  const int col = lane & 15, quad = lane >> 4;

  __shared__ __align__(1024) char smem[40960];
  auto Qs = (unsigned short(*)[128][8])smem;           // [16][128][8] phase 0 (32KB)
  auto Ks = (unsigned short(*)[128])smem;              // [64][128]  16KB
  auto Vs = (unsigned short(*)[64])(smem + 16384);     // [128][64]  16KB
  auto Ps = (unsigned short(*)[64])(smem + 32768);     // [64][64]    8KB

  // ---- stage Q tile (128 x 128) ----
  {
    const int row = tid & 127, kc0 = tid >> 7;
    const unsigned short* g =
        qkv + (size_t)(b * T + qt * 128 + row) * LD + h * 128 + kc0 * 8;
    unsigned short* l = &Qs[kc0][row][0];
#pragma unroll
    for (int r = 0; r < 8; ++r) GLDS16(g + r * 16, l + r * 2048);
  }
  __syncthreads();

  bf16x8 qf[2][4];
#pragma unroll
  for (int mi = 0; mi < 2; ++mi)
#pragma unroll
    for (int ks = 0; ks < 4; ++ks)
      qf[mi][ks] = *(const bf16x8*)&Qs[ks * 4 + quad][wave * 32 + mi * 16 + col][0];

  float mrow[2], lrow[2];
  f32x4 oacc[2][8];  // O^T: lane q = wave*32+mi*16+col, d = di*16+quad*4+r
#pragma unroll
  for (int mi = 0; mi < 2; ++mi) { mrow[mi] = -1e30f; lrow[mi] = 0.f; }
#pragma unroll
  for (int mi = 0; mi < 2; ++mi)
#pragma unroll
    for (int d = 0; d < 8; ++d) oacc[mi][d] = (f32x4){0.f, 0.f, 0.f, 0.f};

  const float scale = 0.08838834764831845f;  // 1/sqrt(128)
  const float l2e = 1.4426950408889634f;
  const float c1 = scale * l2e;

  // staging constants (coalesced + XOR swizzle, r-invariant)
  const int krow0 = tid >> 4;                       // 0..15  (K: 16 lanes/row)
  const int kgch  = (tid & 15) ^ ((tid >> 4) & 15); // K chunk 0..15
  const int vrow0 = tid >> 3;                       // 0..31  (V: 8 lanes/row)
  const int vgch  = (tid & 7) ^ ((tid >> 3) & 7);   // V chunk 0..7
  unsigned short* Klin = &Ks[0][0] + tid * 8;
  unsigned short* Vlin = &Vs[0][0] + tid * 8;

  const int rq  = wave * 16 + col;  // Ps transit row (wave-private)
  const int c14 = col & 14;         // even XOR keeps 16B read pairs adjacent

  for (int s0 = 0; s0 < T; s0 += 64) {
    __syncthreads();
    // ---- stage K tile [64 s][128 d]: 4 GLDS, 16 full lines each ----
    {
      const unsigned short* g =
          qkv + (size_t)(b * T + s0 + krow0) * LD + 4096 + kvh * 128 + kgch * 8;
#pragma unroll
      for (int r = 0; r < 4; ++r)
        GLDS16(g + (size_t)r * 16 * LD, Klin + r * 2048);
      // ---- stage V^T tile [128 d][64 s]: 4 GLDS ----
      const unsigned short* gv =
          vt + (size_t)((b * 8 + kvh) * 128 + vrow0) * T + s0 + vgch * 8;
#pragma unroll
      for (int r = 0; r < 4; ++r)
        GLDS16(gv + (size_t)r * 32 * T, Vlin + r * 2048);
    }
    __syncthreads();

    // ---- scores transposed: S^T = K·Q^T (A=K-frag, B=Q-frag) ----
    // sacc[mi][j][r] = S[q = wave*32+mi*16+col][s = 16j + quad*4 + r]
    f32x4 sacc[2][4];
#pragma unroll
    for (int mi = 0; mi < 2; ++mi)
#pragma unroll
      for (int j = 0; j < 4; ++j) sacc[mi][j] = (f32x4){0.f, 0.f, 0.f, 0.f};
#pragma unroll
    for (int ks = 0; ks < 4; ++ks) {
      bf16x8 ak[4];
#pragma unroll
      for (int j = 0; j < 4; ++j)
        ak[j] = *(const bf16x8*)&Ks[j * 16 + col][((ks * 4 + quad) ^ col) * 8];
#pragma unroll
      for (int mi = 0; mi < 2; ++mi)
#pragma unroll
        for (int j = 0; j < 4; ++j)
          sacc[mi][j] = __builtin_amdgcn_mfma_f32_16x16x32_bf16(
              ak[j], qf[mi][ks], sacc[mi][j], 0, 0, 0);
    }

    // ---- online softmax + P transit (per mi: write Ps -> read bp regs) ----
    bf16x8 bp[2][2];
#pragma unroll
    for (int mi = 0; mi < 2; ++mi) {
      float mx = sacc[mi][0][0];
#pragma unroll
      for (int j = 0; j < 4; ++j)
#pragma unroll
        for (int r = 0; r < 4; ++r) mx = fmaxf(mx, sacc[mi][j][r]);
      mx = fmaxf(mx, __shfl_xor(mx, 16));
      mx = fmaxf(mx, __shfl_xor(mx, 32));
      mx *= scale;
      float mold = mrow[mi];
      float mnew = fmaxf(mold, mx);
      float alpha = exp2f((mold - mnew) * l2e);
      mrow[mi] = mnew;
      const float mml = mnew * l2e;
      float rsum = 0.f;
#pragma unroll
      for (int j = 0; j < 4; ++j) {
        float p0 = exp2f(sacc[mi][j][0] * c1 - mml);
        float p1 = exp2f(sacc[mi][j][1] * c1 - mml);
        float p2 = exp2f(sacc[mi][j][2] * c1 - mml);
        float p3 = exp2f(sacc[mi][j][3] * c1 - mml);
        rsum += (p0 + p1) + (p2 + p3);
        uint2 pk;
        pk.x = cvt_pk_bf16(p0, p1);
        pk.y = cvt_pk_bf16(p2, p3);
        const int ws = (j * 4 + quad) ^ c14;          // 8B slot, swizzled
        *(uint2*)&Ps[rq][ws * 4] = pk;                // ds_write_b64
      }
      // read back this mi's P fragments before next mi reuses the rows
      bp[mi][0] = *(const bf16x8*)&Ps[rq][((quad * 2) ^ c14) * 4];
      bp[mi][1] = *(const bf16x8*)&Ps[rq][((8 + quad * 2) ^ c14) * 4];
      rsum += __shfl_xor(rsum, 16);
      rsum += __shfl_xor(rsum, 32);
      lrow[mi] = lrow[mi] * alpha + rsum;
#pragma unroll
      for (int di = 0; di < 8; ++di) {
#pragma unroll
        for (int r = 0; r < 4; ++r) oacc[mi][di][r] *= alpha;
      }
    }

    // ---- O^T += V^T · P  (A=V^T-frag from Vs, B=P-frag regs) ----
    // va is mi-invariant: load once per (ks,di), reuse for both mi.
#pragma unroll
    for (int ks = 0; ks < 2; ++ks) {
#pragma unroll
      for (int di = 0; di < 8; ++di) {
        bf16x8 va = *(const bf16x8*)
            &Vs[di * 16 + col][(((ks * 4 + quad) ^ (col & 7))) * 8];
#pragma unroll
        for (int mi = 0; mi < 2; ++mi)
          oacc[mi][di] = __builtin_amdgcn_mfma_f32_16x16x32_bf16(
              va, bp[mi][ks], oacc[mi][di], 0, 0, 0);
      }
    }
  }

  // ---- epilogue: ctx[b*T + q][h*128 + d] = O^T / l (transposed scatter) ----
#pragma unroll
  for (int mi = 0; mi < 2; ++mi) {
    float inv = 1.0f / lrow[mi];
    int row = qt * 128 + wave * 32 + mi * 16 + col;
    unsigned short* cp = ctx + (size_t)(b * T + row) * 4096 + h * 128;
#pragma unroll
    for (int di = 0; di < 8; ++di) {
      uint2 o;
      o.x = cvt_pk_bf16(oacc[mi][di][0] * inv, oacc[mi][di][1] * inv);
      o.y = cvt_pk_bf16(oacc[mi][di][2] * inv, oacc[mi][di][3] * inv);
      *(uint2*)(cp + di * 16 + quad * 4) = o;
    }
  }
}

// ---------------------------------------------------------------------------
// launch
// ---------------------------------------------------------------------------
extern "C" void kernel_launch(void* const* d_in, const int* in_sizes, int n_in,
                              void* d_out, int out_size, void* d_ws,
                              size_t ws_size, hipStream_t stream) {
  const float* x  = (const float*)d_in[0];
  const float* wq = (const float*)d_in[1];
  const float* wk = (const float*)d_in[2];
  const float* wv = (const float*)d_in[3];
  const float* wo = (const float*)d_in[4];
  const float* fc = (const float*)d_in[5];
  const float* fs = (const float*)d_in[6];
  float* out = (float*)d_out;

  char* ws = (char*)d_ws;
  unsigned short* xb  = (unsigned short*)(ws);
  unsigned short* wb  = (unsigned short*)(ws + 33554432);
  unsigned short* qkv = (unsigned short*)(ws + 33554432 + 50331648);
  unsigned short* vtp = (unsigned short*)(ws + 33554432 + 50331648 + 50331648);

  cast_f32_bf16<<<16384, 256, 0, stream>>>(x, xb, 4194304);
  cast_f32_bf16<<<16384, 256, 0, stream>>>(wq, wb, 4194304);
  cast_f32_bf16<<<4096, 256, 0, stream>>>(wk, wb + 16777216, 1048576);
  cast_f32_bf16<<<4096, 256, 0, stream>>>(wv, wb + 20971520, 1048576);

  dim3 g1(48, 32);
  gemm_bt<unsigned short><<<g1, 256, 0, stream>>>(xb, wb, qkv, 4096, 6144, 4096);

  cast_f32_bf16<<<16384, 256, 0, stream>>>(wo, wb, 4194304);  // reuse region B

  rope_qk<<<10240, 256, 0, stream>>>(qkv, fc, fs);

  dim3 g2(32, 2, 16);
  transpose_v<<<g2, 256, 0, stream>>>(qkv, vtp);

  dim3 g3(16, 32, 2);
  attn<<<g3, 256, 0, stream>>>(qkv, vtp, xb);  // ctx -> region A

  dim3 g4(32, 32);
  gemm_bt<float><<<g4, 256, 0, stream>>>(xb, wb, out, 4096, 4096, 4096);
}

// Round 15
// 815.814 us; speedup vs baseline: 1.3510x; 1.3510x over previous
//
#include <hip/hip_runtime.h>
#include <hip/hip_bf16.h>
#include <cstdint>

// ---------------------------------------------------------------------------
// Attention block, bf16 MFMA pipeline:
//   cast -> fused QKV GEMM -> RoPE -> V transpose -> flash attention -> O GEMM
// Shapes: B=2 T=2048 DIM=4096 H=32 KVH=8 D=128, no mask, start_pos=0.
// KV mapping: jnp.tile -> Q-head h attends KV-head (h % 8).
// R6 (measured 821.3us): va-hoist + cvt_pk + vectorized rope. attn 232us,
//   VGPR=108, LDS=51200 (3 blocks/CU).
// R8 (measured 1102us, FAILED perf): launch_bounds(256,4) forced VGPR 108->64
//   -> scratch spills (WRITE_SIZE 32MB->615MB, FETCH 120MB->1.2GB), attn
//   454us. GEMM XCD swizzle also implicated (~-59us non-attn).
// R14 (resubmit after broker timeout): keep Ps[64][64] 8KB transit
//   (LDS=40960 -> 4 blocks/CU by LDS), but launch_bounds back to (256,2) so
//   compiler allocates ~108 VGPR (<=128 -> HW still permits 16 waves/CU; no
//   spills). GEMM swizzle reverted to plain blockIdx.
// ---------------------------------------------------------------------------

typedef short bf16x8 __attribute__((ext_vector_type(8)));   // 8 bf16 = 4 VGPRs
typedef float f32x4  __attribute__((ext_vector_type(4)));

__device__ __forceinline__ float b2f(unsigned short h) {
  union { uint32_t u; float f; } v; v.u = ((uint32_t)h) << 16; return v.f;
}
__device__ __forceinline__ unsigned short f2b(float f) {
  union { float f; uint32_t u; } v; v.f = f;
  uint32_t r = (v.u + 0x7FFFu + ((v.u >> 16) & 1u)) >> 16;
  return (unsigned short)r;
}
// packed f32x2 -> bf16x2 (RTNE) in one instruction (T12 recipe)
__device__ __forceinline__ uint32_t cvt_pk_bf16(float lo, float hi) {
  uint32_t r;
  asm("v_cvt_pk_bf16_f32 %0, %1, %2" : "=v"(r) : "v"(lo), "v"(hi));
  return r;
}
__device__ __forceinline__ float lo2f(uint32_t u) {
  union { uint32_t u; float f; } w; w.u = u << 16; return w.f;
}
__device__ __forceinline__ float hi2f(uint32_t u) {
  union { uint32_t u; float f; } w; w.u = u & 0xffff0000u; return w.f;
}

#define GLDS16(gp, lp)                                                        \
  __builtin_amdgcn_global_load_lds(                                           \
      (const __attribute__((address_space(1))) unsigned int*)(gp),            \
      (__attribute__((address_space(3))) unsigned int*)(lp), 16, 0, 0)

// ---------------------------------------------------------------------------
// fp32 -> bf16 cast, 4 elements/thread
// ---------------------------------------------------------------------------
__global__ __launch_bounds__(256) void cast_f32_bf16(
    const float* __restrict__ in, unsigned short* __restrict__ out, int n4) {
  int i = blockIdx.x * 256 + threadIdx.x;
  if (i < n4) {
    float4 v = ((const float4*)in)[i];
    ushort4 o;
    o.x = f2b(v.x); o.y = f2b(v.y); o.z = f2b(v.z); o.w = f2b(v.w);
    ((ushort4*)out)[i] = o;
  }
}

// ---------------------------------------------------------------------------
// GEMM  C[m,n] = sum_k A[m,k]*B[n,k]  (R14: swizzle reverted — plain blockIdx)
// ---------------------------------------------------------------------------
__device__ __forceinline__ void stout(float* p, float v) { *p = v; }
__device__ __forceinline__ void stout(unsigned short* p, float v) { *p = f2b(v); }

template <typename OUT>
__global__ __launch_bounds__(256, 2) void gemm_bt(
    const unsigned short* __restrict__ A, const unsigned short* __restrict__ B,
    OUT* __restrict__ C, int M, int N, int K) {
  __shared__ __align__(16) unsigned short As[128][64];  // 16 KB
  __shared__ __align__(16) unsigned short Bs[128][64];  // 16 KB

  const int tid  = threadIdx.x;
  const int lane = tid & 63;
  const int wave = tid >> 6;
  const int col  = lane & 15;
  const int quad = lane >> 4;
  const int bm = blockIdx.y * 128;
  const int bn = blockIdx.x * 128;
  const int wm = (wave & 1) * 64;
  const int wn = (wave >> 1) * 64;

  f32x4 acc[4][4];
#pragma unroll
  for (int i = 0; i < 4; ++i)
#pragma unroll
    for (int j = 0; j < 4; ++j) acc[i][j] = (f32x4){0.f, 0.f, 0.f, 0.f};

  const int srow0  = tid >> 3;                    // 0..31
  const int gchunk = (tid & 7) ^ ((tid >> 3) & 7);
  const unsigned short* Ag = A + (size_t)(bm + srow0) * K + gchunk * 8;
  const unsigned short* Bg = B + (size_t)(bn + srow0) * K + gchunk * 8;
  unsigned short* Al = &As[0][0] + tid * 8;
  unsigned short* Bl = &Bs[0][0] + tid * 8;

  for (int k0 = 0; k0 < K; k0 += 64) {
    __syncthreads();
#pragma unroll
    for (int r = 0; r < 4; ++r) {
      GLDS16(Ag + k0 + (size_t)r * 32 * K, Al + r * 2048);
      GLDS16(Bg + k0 + (size_t)r * 32 * K, Bl + r * 2048);
    }
    __syncthreads();
#pragma unroll
    for (int ks = 0; ks < 2; ++ks) {
      bf16x8 a[4], b[4];
      const int slot = ((ks * 4 + quad) ^ (col & 7)) * 8;
#pragma unroll
      for (int i = 0; i < 4; ++i)
        a[i] = *(const bf16x8*)&As[wm + i * 16 + col][slot];
#pragma unroll
      for (int j = 0; j < 4; ++j)
        b[j] = *(const bf16x8*)&Bs[wn + j * 16 + col][slot];
#pragma unroll
      for (int i = 0; i < 4; ++i)
#pragma unroll
        for (int j = 0; j < 4; ++j)
          acc[i][j] = __builtin_amdgcn_mfma_f32_16x16x32_bf16(a[i], b[j],
                                                              acc[i][j], 0, 0, 0);
    }
  }

#pragma unroll
  for (int i = 0; i < 4; ++i) {
    int row = bm + wm + i * 16 + quad * 4;
#pragma unroll
    for (int j = 0; j < 4; ++j) {
      int cc = bn + wn + j * 16 + col;
#pragma unroll
      for (int r2 = 0; r2 < 4; ++r2)
        stout(C + (size_t)(row + r2) * N + cc, acc[i][j][r2]);
    }
  }
}

// ---------------------------------------------------------------------------
// RoPE in-place on qkv (4096 rows x 6144 cols): heads 0..31 = q, 32..39 = k.
// 4 rotations (16B) per thread; cvt_pk packing.
// grid: 4096*640/256 = 10240 blocks.
// ---------------------------------------------------------------------------
__global__ __launch_bounds__(256) void rope_qk(
    unsigned short* __restrict__ qkv, const float* __restrict__ cosT,
    const float* __restrict__ sinT) {
  int idx = blockIdx.x * 256 + threadIdx.x;  // < 4096*640
  int m = idx / 640;
  int p = idx - m * 640;                     // group of 4 pairs
  int head = p >> 4, i4 = p & 15;            // 16 groups of 4 pairs per head
  int t = m & 2047;
  unsigned short* ptr = qkv + (size_t)m * 6144 + head * 128 + i4 * 8;
  uint4 v = *(const uint4*)ptr;              // 4 (x,y) bf16 pairs
  float4 c = *(const float4*)&cosT[t * 64 + i4 * 4];
  float4 s = *(const float4*)&sinT[t * 64 + i4 * 4];
  float x0 = lo2f(v.x), y0 = hi2f(v.x);
  float x1 = lo2f(v.y), y1 = hi2f(v.y);
  float x2 = lo2f(v.z), y2 = hi2f(v.z);
  float x3 = lo2f(v.w), y3 = hi2f(v.w);
  uint4 o;
  o.x = cvt_pk_bf16(x0 * c.x - y0 * s.x, x0 * s.x + y0 * c.x);
  o.y = cvt_pk_bf16(x1 * c.y - y1 * s.y, x1 * s.y + y1 * c.y);
  o.z = cvt_pk_bf16(x2 * c.z - y2 * s.z, x2 * s.z + y2 * c.z);
  o.w = cvt_pk_bf16(x3 * c.w - y3 * s.w, x3 * s.w + y3 * c.w);
  *(uint4*)ptr = o;
}

// ---------------------------------------------------------------------------
// V transpose: vt[(b*8+kvh)*128 + d][s] = qkv[b*2048+s][5120 + kvh*128 + d]
// ---------------------------------------------------------------------------
__global__ __launch_bounds__(256) void transpose_v(
    const unsigned short* __restrict__ qkv, unsigned short* __restrict__ vt) {
  __shared__ unsigned short tile[64][72];
  int b = blockIdx.z >> 3, kvh = blockIdx.z & 7;
  int s0 = blockIdx.x * 64, d0 = blockIdx.y * 64;
  int tc = threadIdx.x & 63, tr = threadIdx.x >> 6;  // tr 0..3
#pragma unroll
  for (int r = 0; r < 16; ++r) {
    int row = r * 4 + tr;  // s within tile
    tile[row][tc] =
        qkv[(size_t)(b * 2048 + s0 + row) * 6144 + 5120 + kvh * 128 + d0 + tc];
  }
  __syncthreads();
#pragma unroll
  for (int r = 0; r < 16; ++r) {
    int drow = r * 4 + tr;  // d within tile
    vt[(size_t)((b * 8 + kvh) * 128 + d0 + drow) * 2048 + s0 + tc] =
        tile[tc][drow];
  }
}

// ---------------------------------------------------------------------------
// Flash attention, transposed-score formulation.
// grid (qt=16, h=32, b=2), 256 threads (4 waves), S-tile 64.
// S^T = K·Q^T  : lane owns Q-row q = wave*32+mi*16+(lane&15); 16 scores
//                in-lane per tile -> in-lane max/sum + shfl_xor(16,32).
// P transit: per-mi-reused Ps[64][64] (8KB), slot-XOR swizzle:
//   row rq = wave*16+col (wave-private), 8B slot = (j*4+quad) ^ (col&14).
//   Write 4x ds_write_b64 -> read 2x ds_read_b128 -> next mi reuses rows
//   (same-wave DS in-order).
// O^T = V^T·P  : A-frag from Vs (V^T tile, hoisted over mi), B-frag = bp regs.
// LDS: Ks 16KB + Vs 16KB + Ps 8KB = 40960 B -> 4 blocks/CU by LDS.
// launch_bounds(256,2): natural VGPR (~108 <= 128) so HW still allows 16
// waves/CU — R8's (256,4) forced 64 VGPR and spilled (615MB scratch writes).
// ---------------------------------------------------------------------------
__global__ __launch_bounds__(256, 2) void attn(
    const unsigned short* __restrict__ qkv, const unsigned short* __restrict__ vt,
    unsigned short* __restrict__ ctx) {
  constexpr int T = 2048, LD = 6144;
  const int qt = blockIdx.x, h = blockIdx.y, b = blockIdx.z;
  const int kvh = h & 7;  // jnp.tile semantics
  const int tid = threadIdx.x, lane = tid & 63, wave = tid >> 6;
  const int col = lane & 15, quad = lane >> 4;

  __shared__ __align__(1024) char smem[40960];
  auto Qs = (unsigned short(*)[128][8])smem;           // [16][128][8] phase 0 (32KB)
  auto Ks = (unsigned short(*)[128])smem;              // [64][128]  16KB
  auto Vs = (unsigned short(*)[64])(smem + 16384);     // [128][64]  16KB
  auto Ps = (unsigned short(*)[64])(smem + 32768);     // [64][64]    8KB

  // ---- stage Q tile (128 x 128) ----
  {
    const int row = tid & 127, kc0 = tid >> 7;
    const unsigned short* g =
        qkv + (size_t)(b * T + qt * 128 + row) * LD + h * 128 + kc0 * 8;
    unsigned short* l = &Qs[kc0][row][0];
#pragma unroll
    for (int r = 0; r < 8; ++r) GLDS16(g + r * 16, l + r * 2048);
  }
  __syncthreads();

  bf16x8 qf[2][4];
#pragma unroll
  for (int mi = 0; mi < 2; ++mi)
#pragma unroll
    for (int ks = 0; ks < 4; ++ks)
      qf[mi][ks] = *(const bf16x8*)&Qs[ks * 4 + quad][wave * 32 + mi * 16 + col][0];

  float mrow[2], lrow[2];
  f32x4 oacc[2][8];  // O^T: lane q = wave*32+mi*16+col, d = di*16+quad*4+r
#pragma unroll
  for (int mi = 0; mi < 2; ++mi) { mrow[mi] = -1e30f; lrow[mi] = 0.f; }
#pragma unroll
  for (int mi = 0; mi < 2; ++mi)
#pragma unroll
    for (int d = 0; d < 8; ++d) oacc[mi][d] = (f32x4){0.f, 0.f, 0.f, 0.f};

  const float scale = 0.08838834764831845f;  // 1/sqrt(128)
  const float l2e = 1.4426950408889634f;
  const float c1 = scale * l2e;

  // staging constants (coalesced + XOR swizzle, r-invariant)
  const int krow0 = tid >> 4;                       // 0..15  (K: 16 lanes/row)
  const int kgch  = (tid & 15) ^ ((tid >> 4) & 15); // K chunk 0..15
  const int vrow0 = tid >> 3;                       // 0..31  (V: 8 lanes/row)
  const int vgch  = (tid & 7) ^ ((tid >> 3) & 7);   // V chunk 0..7
  unsigned short* Klin = &Ks[0][0] + tid * 8;
  unsigned short* Vlin = &Vs[0][0] + tid * 8;

  const int rq  = wave * 16 + col;  // Ps transit row (wave-private)
  const int c14 = col & 14;         // even XOR keeps 16B read pairs adjacent

  for (int s0 = 0; s0 < T; s0 += 64) {
    __syncthreads();
    // ---- stage K tile [64 s][128 d]: 4 GLDS, 16 full lines each ----
    {
      const unsigned short* g =
          qkv + (size_t)(b * T + s0 + krow0) * LD + 4096 + kvh * 128 + kgch * 8;
#pragma unroll
      for (int r = 0; r < 4; ++r)
        GLDS16(g + (size_t)r * 16 * LD, Klin + r * 2048);
      // ---- stage V^T tile [128 d][64 s]: 4 GLDS ----
      const unsigned short* gv =
          vt + (size_t)((b * 8 + kvh) * 128 + vrow0) * T + s0 + vgch * 8;
#pragma unroll
      for (int r = 0; r < 4; ++r)
        GLDS16(gv + (size_t)r * 32 * T, Vlin + r * 2048);
    }
    __syncthreads();

    // ---- scores transposed: S^T = K·Q^T (A=K-frag, B=Q-frag) ----
    // sacc[mi][j][r] = S[q = wave*32+mi*16+col][s = 16j + quad*4 + r]
    f32x4 sacc[2][4];
#pragma unroll
    for (int mi = 0; mi < 2; ++mi)
#pragma unroll
      for (int j = 0; j < 4; ++j) sacc[mi][j] = (f32x4){0.f, 0.f, 0.f, 0.f};
#pragma unroll
    for (int ks = 0; ks < 4; ++ks) {
      bf16x8 ak[4];
#pragma unroll
      for (int j = 0; j < 4; ++j)
        ak[j] = *(const bf16x8*)&Ks[j * 16 + col][((ks * 4 + quad) ^ col) * 8];
#pragma unroll
      for (int mi = 0; mi < 2; ++mi)
#pragma unroll
        for (int j = 0; j < 4; ++j)
          sacc[mi][j] = __builtin_amdgcn_mfma_f32_16x16x32_bf16(
              ak[j], qf[mi][ks], sacc[mi][j], 0, 0, 0);
    }

    // ---- online softmax + P transit (per mi: write Ps -> read bp regs) ----
    bf16x8 bp[2][2];
#pragma unroll
    for (int mi = 0; mi < 2; ++mi) {
      float mx = sacc[mi][0][0];
#pragma unroll
      for (int j = 0; j < 4; ++j)
#pragma unroll
        for (int r = 0; r < 4; ++r) mx = fmaxf(mx, sacc[mi][j][r]);
      mx = fmaxf(mx, __shfl_xor(mx, 16));
      mx = fmaxf(mx, __shfl_xor(mx, 32));
      mx *= scale;
      float mold = mrow[mi];
      float mnew = fmaxf(mold, mx);
      float alpha = exp2f((mold - mnew) * l2e);
      mrow[mi] = mnew;
      const float mml = mnew * l2e;
      float rsum = 0.f;
#pragma unroll
      for (int j = 0; j < 4; ++j) {
        float p0 = exp2f(sacc[mi][j][0] * c1 - mml);
        float p1 = exp2f(sacc[mi][j][1] * c1 - mml);
        float p2 = exp2f(sacc[mi][j][2] * c1 - mml);
        float p3 = exp2f(sacc[mi][j][3] * c1 - mml);
        rsum += (p0 + p1) + (p2 + p3);
        uint2 pk;
        pk.x = cvt_pk_bf16(p0, p1);
        pk.y = cvt_pk_bf16(p2, p3);
        const int ws = (j * 4 + quad) ^ c14;          // 8B slot, swizzled
        *(uint2*)&Ps[rq][ws * 4] = pk;                // ds_write_b64
      }
      // read back this mi's P fragments before next mi reuses the rows
      bp[mi][0] = *(const bf16x8*)&Ps[rq][((quad * 2) ^ c14) * 4];
      bp[mi][1] = *(const bf16x8*)&Ps[rq][((8 + quad * 2) ^ c14) * 4];
      rsum += __shfl_xor(rsum, 16);
      rsum += __shfl_xor(rsum, 32);
      lrow[mi] = lrow[mi] * alpha + rsum;
#pragma unroll
      for (int di = 0; di < 8; ++di) {
#pragma unroll
        for (int r = 0; r < 4; ++r) oacc[mi][di][r] *= alpha;
      }
    }

    // ---- O^T += V^T · P  (A=V^T-frag from Vs, B=P-frag regs) ----
    // va is mi-invariant: load once per (ks,di), reuse for both mi.
#pragma unroll
    for (int ks = 0; ks < 2; ++ks) {
#pragma unroll
      for (int di = 0; di < 8; ++di) {
        bf16x8 va = *(const bf16x8*)
            &Vs[di * 16 + col][(((ks * 4 + quad) ^ (col & 7))) * 8];
#pragma unroll
        for (int mi = 0; mi < 2; ++mi)
          oacc[mi][di] = __builtin_amdgcn_mfma_f32_16x16x32_bf16(
              va, bp[mi][ks], oacc[mi][di], 0, 0, 0);
      }
    }
  }

  // ---- epilogue: ctx[b*T + q][h*128 + d] = O^T / l (transposed scatter) ----
#pragma unroll
  for (int mi = 0; mi < 2; ++mi) {
    float inv = 1.0f / lrow[mi];
    int row = qt * 128 + wave * 32 + mi * 16 + col;
    unsigned short* cp = ctx + (size_t)(b * T + row) * 4096 + h * 128;
#pragma unroll
    for (int di = 0; di < 8; ++di) {
      uint2 o;
      o.x = cvt_pk_bf16(oacc[mi][di][0] * inv, oacc[mi][di][1] * inv);
      o.y = cvt_pk_bf16(oacc[mi][di][2] * inv, oacc[mi][di][3] * inv);
      *(uint2*)(cp + di * 16 + quad * 4) = o;
    }
  }
}

// ---------------------------------------------------------------------------
// launch
// ---------------------------------------------------------------------------
extern "C" void kernel_launch(void* const* d_in, const int* in_sizes, int n_in,
                              void* d_out, int out_size, void* d_ws,
                              size_t ws_size, hipStream_t stream) {
  const float* x  = (const float*)d_in[0];
  const float* wq = (const float*)d_in[1];
  const float* wk = (const float*)d_in[2];
  const float* wv = (const float*)d_in[3];
  const float* wo = (const float*)d_in[4];
  const float* fc = (const float*)d_in[5];
  const float* fs = (const float*)d_in[6];
  float* out = (float*)d_out;

  char* ws = (char*)d_ws;
  unsigned short* xb  = (unsigned short*)(ws);
  unsigned short* wb  = (unsigned short*)(ws + 33554432);
  unsigned short* qkv = (unsigned short*)(ws + 33554432 + 50331648);
  unsigned short* vtp = (unsigned short*)(ws + 33554432 + 50331648 + 50331648);

  cast_f32_bf16<<<16384, 256, 0, stream>>>(x, xb, 4194304);
  cast_f32_bf16<<<16384, 256, 0, stream>>>(wq, wb, 4194304);
  cast_f32_bf16<<<4096, 256, 0, stream>>>(wk, wb + 16777216, 1048576);
  cast_f32_bf16<<<4096, 256, 0, stream>>>(wv, wb + 20971520, 1048576);

  dim3 g1(48, 32);
  gemm_bt<unsigned short><<<g1, 256, 0, stream>>>(xb, wb, qkv, 4096, 6144, 4096);

  cast_f32_bf16<<<16384, 256, 0, stream>>>(wo, wb, 4194304);  // reuse region B

  rope_qk<<<10240, 256, 0, stream>>>(qkv, fc, fs);

  dim3 g2(32, 2, 16);
  transpose_v<<<g2, 256, 0, stream>>>(qkv, vtp);

  dim3 g3(16, 32, 2);
  attn<<<g3, 256, 0, stream>>>(qkv, vtp, xb);  // ctx -> region A

  dim3 g4(32, 32);
  gemm_bt<float><<<g4, 256, 0, stream>>>(xb, wb, out, 4096, 4096, 4096);
}